// Round 7
// baseline (506.505 us; speedup 1.0000x reference)
//
#include <hip/hip_runtime.h>
#include <hip/hip_bf16.h>
#include <math.h>

#define D 256
#define H 4
#define DH 64
#define NOUT 256

typedef short bf16x8 __attribute__((ext_vector_type(8)));
typedef float f32x4 __attribute__((ext_vector_type(4)));

__device__ __forceinline__ ushort f2bf(float f){
  uint b = __float_as_uint(f);
  b += 0x7FFF + ((b >> 16) & 1);   // round-to-nearest-even
  return (ushort)(b >> 16);
}
__device__ __forceinline__ float bf2f(ushort u){
  return __uint_as_float(((uint)u) << 16);
}

// DPP-based sum reduction over 32 lanes (rows of 16 via row_ror, then xor-16).
__device__ __forceinline__ float redux32(float v){
  int t;
  t = __builtin_amdgcn_update_dpp(0, __float_as_int(v), 0x121, 0xF, 0xF, true); v += __int_as_float(t); // row_ror:1
  t = __builtin_amdgcn_update_dpp(0, __float_as_int(v), 0x122, 0xF, 0xF, true); v += __int_as_float(t); // row_ror:2
  t = __builtin_amdgcn_update_dpp(0, __float_as_int(v), 0x124, 0xF, 0xF, true); v += __int_as_float(t); // row_ror:4
  t = __builtin_amdgcn_update_dpp(0, __float_as_int(v), 0x128, 0xF, 0xF, true); v += __int_as_float(t); // row_ror:8
  v += __shfl_xor(v, 16, 64);
  return v;
}

// ---------------- K1: fused count_winner + prep_weights ----------------
// blocks [0, nCW): count members per segment + winner per pdg key
// blocks [nCW, nCW+285): weight prep (conv3 / small dots / Wo transpose)
__global__ __launch_bounds__(256) void k1_count_prep(
    const int* __restrict__ seg, int* __restrict__ counts,
    const int* __restrict__ pdgkey, int* __restrict__ winner, int M, int C, int nCW,
    const float* __restrict__ Wq, const float* __restrict__ Wk,
    const float* __restrict__ Wv, const float* __restrict__ Wo,
    const float* __restrict__ bq, const float* __restrict__ bk,
    const float* __restrict__ bv,
    ushort* __restrict__ Wq16, ushort* __restrict__ Wk16, ushort* __restrict__ Wv16,
    ushort* __restrict__ WoT16,
    float* __restrict__ wqbk, float* __restrict__ bvo,
    float* __restrict__ bqk, float* __restrict__ cbh){
  __shared__ float t[64][65];
  int bid = blockIdx.x, tid = threadIdx.x;
  if (bid < nCW){
    int i = bid*256 + tid;
    if (i < M){ int s = seg[i]; if (s >= 0 && s < C) atomicAdd(&counts[s], 1); }
    if (i < C){ int tt = pdgkey[i]; if (tt >= 0 && tt < C) atomicMax(&winner[tt], i); }
    return;
  }
  int b = bid - nCW;
  if (b < 256){
    int id = b*256 + tid;
    Wq16[id] = f2bf(Wq[id]);
    Wk16[id] = f2bf(Wk[id]);
    Wv16[id] = f2bf(Wv[id]);
  } else if (b < 269){
    int id = (b - 256)*256 + tid;
    if (id < 1024){
      int h = id >> 8, k = id & 255;
      float s = 0.f;
      for (int d = 0; d < DH; d++) s += Wq[(size_t)k*256 + h*64 + d] * bk[h*64 + d];
      wqbk[id] = s;
    } else if (id < 2048){
      int tt = id - 1024; int h = tt >> 8, o = tt & 255;
      float s = 0.f;
      for (int d = 0; d < DH; d++) s += bv[h*64 + d] * Wo[(size_t)(h*64 + d)*256 + o];
      bvo[tt] = s;
    } else if (id < 3072){
      int tt = id - 2048; int h = tt >> 8, e = tt & 255;
      float s = 0.f;
      for (int d = 0; d < DH; d++) s += bq[h*64 + d] * Wk[(size_t)e*256 + h*64 + d];
      bqk[tt] = s;
    } else if (id < 3076){
      int h = id - 3072;
      float s = 0.f;
      for (int d = 0; d < DH; d++) s += bq[h*64 + d] * bk[h*64 + d];
      cbh[h] = s;
    }
  } else {
    int b2 = b - 269;
    int bx = b2 & 3, by = b2 >> 2;
    int r = tid >> 6, cc = tid & 63;
    #pragma unroll
    for (int rr = 0; rr < 64; rr += 4)
      t[rr + r][cc] = Wo[(size_t)(by*64 + rr + r)*256 + bx*64 + cc];
    __syncthreads();
    #pragma unroll
    for (int rr = 0; rr < 64; rr += 4)
      WoT16[(size_t)(bx*64 + rr + r)*256 + by*64 + cc] = f2bf(t[cc][rr + r]);
  }
}

// ---------------- K2: single-block hierarchical scan over C counts ----------------
// Produces offsets[0..C] (exclusive prefix) and pos[] copy, in one launch.
__global__ __launch_bounds__(1024) void scan_all(const int* __restrict__ counts,
    int* __restrict__ offsets, int* __restrict__ pos, int C){
  __shared__ int wtot[16];
  __shared__ int wexcl[16];
  __shared__ int bt;
  __shared__ int srun;
  int tid = threadIdx.x, lane = tid & 63, wv = tid >> 6;
  if (tid == 0) srun = 0;
  __syncthreads();
  int nch = (C + 1023) >> 10;
  for (int ch = 0; ch < nch; ch++){
    int i = ch*1024 + tid;
    int v = (i < C) ? counts[i] : 0;
    int x = v;
    #pragma unroll
    for (int d2 = 1; d2 < 64; d2 <<= 1){
      int tt = __shfl_up(x, d2, 64);
      if (lane >= d2) x += tt;
    }
    if (lane == 63) wtot[wv] = x;
    __syncthreads();
    if (wv == 0 && lane < 16){
      int tt = wtot[lane]; int y = tt;
      #pragma unroll
      for (int d2 = 1; d2 < 16; d2 <<= 1){
        int u = __shfl_up(y, d2, 64);
        if (lane >= d2) y += u;
      }
      wexcl[lane] = y - tt;
      if (lane == 15) bt = y;
    }
    __syncthreads();
    if (i < C){ int o = srun + wexcl[wv] + x - v; offsets[i] = o; pos[i] = o; }
    __syncthreads();
    if (tid == 0) srun += bt;
    __syncthreads();
  }
  if (tid == 0) offsets[C] = srun;
}

// ---------------- 64x64 MFMA GEMM body (device fn, bf16 out, no bias) ----------------
__device__ __forceinline__ void gemm64_body(
    ushort (*As)[72], ushort (*Bs)[72],
    const ushort* __restrict__ A, int sA, int acol_h,
    const ushort* __restrict__ Bt, int sBt, int btrow_h, int btcol_h,
    ushort* __restrict__ Out, int sOut, int outrow_h, int outcol_h,
    int Mr, int K, int bx, int by, int hz, int tid){
  int m0 = bx*64;
  int acol0  = acol_h*hz;
  int btrow0 = by*64 + btrow_h*hz;
  int btcol0 = btcol_h*hz;
  int outrow0 = outrow_h*hz;
  int outcol0 = by*64 + outcol_h*hz;
  int w = tid >> 6, lane = tid & 63, quad = lane >> 4, l16 = lane & 15;
  int r1 = tid >> 3, c8 = (tid & 7)*8;
  f32x4 acc[4] = {};
  for (int k0 = 0; k0 < K; k0 += 64){
    const ushort* ga = A + (size_t)(m0 + r1)*sA + acol0 + k0 + c8;
    uint4 v1 = make_uint4(0,0,0,0), v2 = make_uint4(0,0,0,0);
    if (m0 + r1 < Mr)      v1 = *(const uint4*)ga;
    if (m0 + r1 + 32 < Mr) v2 = *(const uint4*)(ga + (size_t)32*sA);
    *(uint4*)&As[r1][c8]      = v1;
    *(uint4*)&As[r1+32][c8]   = v2;
    const ushort* gb = Bt + (size_t)(btrow0 + r1)*sBt + btcol0 + k0 + c8;
    *(uint4*)&Bs[r1][c8]      = *(const uint4*)gb;
    *(uint4*)&Bs[r1+32][c8]   = *(const uint4*)(gb + (size_t)32*sBt);
    __syncthreads();
    #pragma unroll
    for (int ks = 0; ks < 2; ks++){
      bf16x8 bfr = *(const bf16x8*)&Bs[w*16 + l16][ks*32 + quad*8];
      #pragma unroll
      for (int mt = 0; mt < 4; mt++){
        bf16x8 afr = *(const bf16x8*)&As[mt*16 + l16][ks*32 + quad*8];
        acc[mt] = __builtin_amdgcn_mfma_f32_16x16x32_bf16(afr, bfr, acc[mt], 0, 0, 0);
      }
    }
    __syncthreads();
  }
  int col = outcol0 + w*16 + l16;
  #pragma unroll
  for (int mt = 0; mt < 4; mt++){
    #pragma unroll
    for (int r = 0; r < 4; r++){
      int row = m0 + mt*16 + quad*4 + r;
      if (row < Mr)
        Out[(size_t)(outrow0 + row)*sOut + col] = f2bf(acc[mt][r]);
    }
  }
}

// ---------------- K3: fused fill + 2 small GEMMs + gather_ag ----------------
// blocks [0, nF): fill (rows[p] = astkey[i])
// blocks [nF, nF+128): Gt (hz 0..3) and Zt (hz 4..7) small GEMMs
// blocks [nF+128, ...): gather Ag rows + qb precompute
__global__ __launch_bounds__(256) void k3_fill_gemm_gather(
    const int* __restrict__ seg, const int* __restrict__ astkey,
    int* __restrict__ pos, int* __restrict__ rows, int M, int nF,
    const ushort* __restrict__ Wk16, const ushort* __restrict__ Wq16,
    const ushort* __restrict__ WoT16, const ushort* __restrict__ Wv16,
    ushort* __restrict__ Gt16, ushort* __restrict__ Zt16,
    const float* __restrict__ enc, const int* __restrict__ rootval,
    const int* __restrict__ winner,
    const float* __restrict__ wqbk, const float* __restrict__ cbh,
    ushort* __restrict__ Ag, float* __restrict__ qb, int C){
  __shared__ __align__(16) ushort As[64][72];
  __shared__ __align__(16) ushort Bs[64][72];
  int bid = blockIdx.x, tid = threadIdx.x;
  if (bid < nF){
    int i = bid*256 + tid;
    if (i < M){
      int s = seg[i];
      if (s >= 0 && s < C){ int p = atomicAdd(&pos[s], 1); rows[p] = astkey[i]; }
    }
    return;
  }
  if (bid < nF + 128){
    int b2 = bid - nF;
    int bx = b2 & 3, by = (b2 >> 2) & 3, hz = b2 >> 4;   // hz 0..7
    if (hz < 4)
      // Gt[(h,e)][k] = sum_d Wq[k,64h+d]*Wk[e,64h+d]
      gemm64_body(As, Bs, Wk16, D, DH,  Wq16, D, 0, DH,  Gt16, D, D, 0,
                  D, DH, bx, by, hz, tid);
    else
      // Zt[o][(h,j)] = sum_d Wv[j,64h+d]*Wo[64h+d,o]
      gemm64_body(As, Bs, WoT16, D, DH,  Wv16, D, 0, DH,  Zt16, H*D, 0, D,
                  D, DH, bx, by, hz - 4, tid);
    return;
  }
  // gather branch
  int id = (bid - nF - 128)*256 + tid;
  int c = id >> 6, g = id & 63;
  if (c >= C) return;
  int w = winner[c];
  float4 v = make_float4(0.f, 0.f, 0.f, 0.f);
  if (w >= 0) v = *(const float4*)(enc + (size_t)rootval[w]*D + g*4);
  ushort4 u; u.x = f2bf(v.x); u.y = f2bf(v.y); u.z = f2bf(v.z); u.w = f2bf(v.w);
  *(ushort4*)(Ag + (size_t)c*D + g*4) = u;
  float b0 = bf2f(u.x), b1 = bf2f(u.y), b2f = bf2f(u.z), b3 = bf2f(u.w);
  float pv[4];
  #pragma unroll
  for (int h = 0; h < 4; h++){
    float4 wv = *(const float4*)(wqbk + h*256 + g*4);
    float p = b0*wv.x + b1*wv.y + b2f*wv.z + b3*wv.w;
    p = redux32(p);
    p += __shfl_xor(p, 32, 64);
    pv[h] = p;
  }
  if (g < 4) qb[c*4 + g] = pv[g] + cbh[g];
}

// ---------------- unified bf16 MFMA GEMM (64x64 tiles; big GEMMs) ----------------
template<bool OUT_BF16>
__global__ __launch_bounds__(256) void mfma_gemm(
    const ushort* __restrict__ A, int sA, int acol_h,
    const ushort* __restrict__ Bt, int sBt, int btrow_h, int btcol_h,
    void* __restrict__ Out, int sOut, int outrow_h, int outcol_h,
    int M, int K,
    const float* __restrict__ bias, const float* __restrict__ beta4,
    const float* __restrict__ bvo4){
  __shared__ __align__(16) ushort As[64][72];
  __shared__ __align__(16) ushort Bs[64][72];
  int tid = threadIdx.x;
  int hz = blockIdx.z;
  int m0 = blockIdx.x*64;
  int acol0  = acol_h*hz;
  int btrow0 = blockIdx.y*64 + btrow_h*hz;
  int btcol0 = btcol_h*hz;
  int outrow0 = outrow_h*hz;
  int outcol0 = blockIdx.y*64 + outcol_h*hz;
  int w = tid >> 6, lane = tid & 63, quad = lane >> 4, l16 = lane & 15;
  int r1 = tid >> 3, c8 = (tid & 7)*8;
  f32x4 acc[4] = {};
  for (int k0 = 0; k0 < K; k0 += 64){
    const ushort* ga = A + (size_t)(m0 + r1)*sA + acol0 + k0 + c8;
    uint4 v1 = make_uint4(0,0,0,0), v2 = make_uint4(0,0,0,0);
    if (m0 + r1 < M)      v1 = *(const uint4*)ga;
    if (m0 + r1 + 32 < M) v2 = *(const uint4*)(ga + (size_t)32*sA);
    *(uint4*)&As[r1][c8]      = v1;
    *(uint4*)&As[r1+32][c8]   = v2;
    const ushort* gb = Bt + (size_t)(btrow0 + r1)*sBt + btcol0 + k0 + c8;
    *(uint4*)&Bs[r1][c8]      = *(const uint4*)gb;
    *(uint4*)&Bs[r1+32][c8]   = *(const uint4*)(gb + (size_t)32*sBt);
    __syncthreads();
    #pragma unroll
    for (int ks = 0; ks < 2; ks++){
      bf16x8 b = *(const bf16x8*)&Bs[w*16 + l16][ks*32 + quad*8];
      #pragma unroll
      for (int mt = 0; mt < 4; mt++){
        bf16x8 a = *(const bf16x8*)&As[mt*16 + l16][ks*32 + quad*8];
        acc[mt] = __builtin_amdgcn_mfma_f32_16x16x32_bf16(a, b, acc[mt], 0, 0, 0);
      }
    }
    __syncthreads();
  }
  int col = outcol0 + w*16 + l16;
  int bcol = btrow0 + w*16 + l16;
  float bval = bias ? bias[bcol] : 0.f;
  #pragma unroll
  for (int mt = 0; mt < 4; mt++){
    #pragma unroll
    for (int r = 0; r < 4; r++){
      int row = m0 + mt*16 + quad*4 + r;
      if (row < M){
        float v = acc[mt][r] + bval;
        if (bvo4){
          v += beta4[row*4+0]*bvo4[0*256 + bcol] + beta4[row*4+1]*bvo4[1*256 + bcol]
             + beta4[row*4+2]*bvo4[2*256 + bcol] + beta4[row*4+3]*bvo4[3*256 + bcol];
        }
        if (OUT_BF16) ((ushort*)Out)[(size_t)(outrow0 + row)*sOut + col] = f2bf(v);
        else          ((float*)Out)[(size_t)(outrow0 + row)*sOut + col] = v;
      }
    }
  }
}

// ---------------- fused per-segment attention pooling (round-5 best) ----------------
// One segment per HALF-WAVE (8 segments per 256-thread block). 4 members per iteration
// with 4-row prefetch.
__global__ __launch_bounds__(256) void seg_attn(const float* __restrict__ enc,
    const int* __restrict__ rows, const int* __restrict__ offsets,
    const ushort* __restrict__ qk16, const float* __restrict__ qb,
    ushort* __restrict__ Shat16, float* __restrict__ beta, int C){
  int lane = threadIdx.x & 63, wave = threadIdx.x >> 6;
  int half = lane >> 5, sl = lane & 31;
  int c = blockIdx.x*8 + wave*2 + half;
  if (c >= C) return;
  float qk[4][8];
  const ushort* qkp = qk16 + (size_t)c*1024 + sl*8;
  #pragma unroll
  for (int h = 0; h < 4; h++){
    uint4 u = *(const uint4*)(qkp + h*256);
    qk[h][0]=__uint_as_float(u.x<<16); qk[h][1]=__uint_as_float(u.x&0xffff0000u);
    qk[h][2]=__uint_as_float(u.y<<16); qk[h][3]=__uint_as_float(u.y&0xffff0000u);
    qk[h][4]=__uint_as_float(u.z<<16); qk[h][5]=__uint_as_float(u.z&0xffff0000u);
    qk[h][6]=__uint_as_float(u.w<<16); qk[h][7]=__uint_as_float(u.w&0xffff0000u);
  }
  float4 qbv = *(const float4*)(qb + (size_t)c*4);
  float qbh[4] = {qbv.x, qbv.y, qbv.z, qbv.w};
  int off = offsets[c];
  int n = offsets[c+1] - off;
  float S[4][8] = {};
  float l[4] = {0.f, 0.f, 0.f, 0.f};
  int hbase = half*32;
  for (int base = 0; base < n; base += 32){
    int cnt = min(32, n - base);
    int xrow = 0;
    if (sl < cnt) xrow = rows[off + base + sl];
    float4 x0[4], x1[4];
    #pragma unroll
    for (int m = 0; m < 4; m++){
      int idx = (m < cnt) ? m : (cnt - 1);
      int r = __shfl(xrow, hbase + idx, 64);
      const float* p = enc + (size_t)r*256 + sl*8;
      x0[m] = *(const float4*)p;
      x1[m] = *(const float4*)(p + 4);
    }
    for (int j = 0; j < cnt; j += 4){
      float4 n0[4], n1[4];
      #pragma unroll
      for (int m = 0; m < 4; m++){ n0[m] = x0[m]; n1[m] = x1[m]; }
      if (j + 4 < cnt){
        #pragma unroll
        for (int m = 0; m < 4; m++){
          int k = j + 4 + m; k = (k < cnt) ? k : (cnt - 1);
          int r = __shfl(xrow, hbase + k, 64);
          const float* p = enc + (size_t)r*256 + sl*8;
          n0[m] = *(const float4*)p;
          n1[m] = *(const float4*)(p + 4);
        }
      }
      float pm[4][4];
      #pragma unroll
      for (int m = 0; m < 4; m++){
        #pragma unroll
        for (int h = 0; h < 4; h++){
          pm[m][h] = x0[m].x*qk[h][0] + x0[m].y*qk[h][1] + x0[m].z*qk[h][2] + x0[m].w*qk[h][3]
                   + x1[m].x*qk[h][4] + x1[m].y*qk[h][5] + x1[m].z*qk[h][6] + x1[m].w*qk[h][7];
        }
      }
      #pragma unroll
      for (int m = 0; m < 4; m++){
        #pragma unroll
        for (int h = 0; h < 4; h++) pm[m][h] = redux32(pm[m][h]);
      }
      #pragma unroll
      for (int m = 0; m < 4; m++){
        bool valid = (j + m) < cnt;
        #pragma unroll
        for (int h = 0; h < 4; h++)
          pm[m][h] = valid ? __expf((pm[m][h] + qbh[h]) * 0.125f) : 0.f;
      }
      #pragma unroll
      for (int h = 0; h < 4; h++)
        l[h] += (pm[0][h] + pm[1][h]) + (pm[2][h] + pm[3][h]);
      #pragma unroll
      for (int m = 0; m < 4; m++){
        #pragma unroll
        for (int h = 0; h < 4; h++){
          float e = pm[m][h];
          S[h][0] += e*x0[m].x; S[h][1] += e*x0[m].y;
          S[h][2] += e*x0[m].z; S[h][3] += e*x0[m].w;
          S[h][4] += e*x1[m].x; S[h][5] += e*x1[m].y;
          S[h][6] += e*x1[m].z; S[h][7] += e*x1[m].w;
        }
      }
      #pragma unroll
      for (int m = 0; m < 4; m++){ x0[m] = n0[m]; x1[m] = n1[m]; }
    }
  }
  float inv[4];
  #pragma unroll
  for (int h = 0; h < 4; h++) inv[h] = 1.f / (l[h] + 1e-9f);
  ushort* sp = Shat16 + (size_t)c*1024 + sl*8;
  #pragma unroll
  for (int h = 0; h < 4; h++){
    float ih = inv[h];
    uint4 o;
    o.x = (uint)f2bf(S[h][0]*ih) | ((uint)f2bf(S[h][1]*ih) << 16);
    o.y = (uint)f2bf(S[h][2]*ih) | ((uint)f2bf(S[h][3]*ih) << 16);
    o.z = (uint)f2bf(S[h][4]*ih) | ((uint)f2bf(S[h][5]*ih) << 16);
    o.w = (uint)f2bf(S[h][6]*ih) | ((uint)f2bf(S[h][7]*ih) << 16);
    *(uint4*)(sp + h*256) = o;
  }
  if (sl == 0){
    beta[c*4+0] = l[0] / (l[0] + 1e-9f);
    beta[c*4+1] = l[1] / (l[1] + 1e-9f);
    beta[c*4+2] = l[2] / (l[2] + 1e-9f);
    beta[c*4+3] = l[3] / (l[3] + 1e-9f);
  }
}

extern "C" void kernel_launch(void* const* d_in, const int* in_sizes, int n_in,
                              void* d_out, int out_size, void* d_ws, size_t ws_size,
                              hipStream_t stream) {
  const float* enc    = (const float*)d_in[0];
  const int*   astkey = (const int*)d_in[1];
  const int*   seg    = (const int*)d_in[2];
  const int*   pdgkey = (const int*)d_in[3];
  const int*   pdgval = (const int*)d_in[4];
  const float* Wq = (const float*)d_in[6];
  const float* bq = (const float*)d_in[7];
  const float* Wk = (const float*)d_in[8];
  const float* bk = (const float*)d_in[9];
  const float* Wv = (const float*)d_in[10];
  const float* bv = (const float*)d_in[11];
  const float* Wo = (const float*)d_in[12];
  const float* bo = (const float*)d_in[13];
  float* out = (float*)d_out;
  const int M = in_sizes[1];
  const int C = in_sizes[3];

  char* p = (char*)d_ws;
  auto alloc = [&](size_t bytes) -> void* {
    void* r = (void*)p;
    p += (bytes + 255) / 256 * 256;
    return r;
  };
  ushort* Ag      = (ushort*)alloc((size_t)C * D * 2);
  ushort* qk16    = (ushort*)alloc((size_t)C * H * D * 2);
  ushort* Shat16  = (ushort*)alloc((size_t)C * H * D * 2);
  float*  beta    = (float*)alloc((size_t)C * H * 4);
  float*  qb      = (float*)alloc((size_t)C * H * 4);
  ushort* Wq16    = (ushort*)alloc((size_t)D * D * 2);
  ushort* Wk16    = (ushort*)alloc((size_t)D * D * 2);
  ushort* Wv16    = (ushort*)alloc((size_t)D * D * 2);
  ushort* WoT16   = (ushort*)alloc((size_t)D * D * 2);
  ushort* Gt16    = (ushort*)alloc((size_t)H * D * D * 2);
  ushort* Zt16    = (ushort*)alloc((size_t)D * H * D * 2);
  float*  wqbk    = (float*)alloc((size_t)H * D * 4);
  float*  bvo     = (float*)alloc((size_t)H * NOUT * 4);
  float*  bqk     = (float*)alloc((size_t)H * D * 4);
  float*  cbh     = (float*)alloc((size_t)H * 4);
  int*   winner   = (int*)alloc((size_t)C * 4);
  int*   counts   = (int*)alloc((size_t)C * 4);
  int*   offsets  = (int*)alloc((size_t)(C + 1) * 4);
  int*   pos      = (int*)alloc((size_t)C * 4);
  int*   rows     = (int*)alloc((size_t)M * 4);

  hipMemsetAsync(winner, 0xFF, (size_t)C * 4, stream);
  hipMemsetAsync(counts, 0, (size_t)C * 4, stream);

  int gM = (M + 255) / 256;
  int gMC = ((M > C ? M : C) + 255) / 256;
  int gAg = (C*64 + 255) / 256;
  int mt = (C + 63) / 64;

  // K1: count/winner + weight prep
  k1_count_prep<<<gMC + 285, 256, 0, stream>>>(
      seg, counts, pdgkey, winner, M, C, gMC,
      Wq, Wk, Wv, Wo, bq, bk, bv,
      Wq16, Wk16, Wv16, WoT16, wqbk, bvo, bqk, cbh);

  // K2: single-block scan -> offsets, pos
  scan_all<<<1, 1024, 0, stream>>>(counts, offsets, pos, C);

  // K3: fill + small GEMMs (Gt, Zt) + gather Ag/qb
  k3_fill_gemm_gather<<<gM + 128 + gAg, 256, 0, stream>>>(
      seg, astkey, pos, rows, M, gM,
      Wk16, Wq16, WoT16, Wv16, Gt16, Zt16,
      enc, pdgval, winner, wqbk, cbh, Ag, qb, C);

  // qk16[c,(h,e)] = Ag[c,:] @ Gt[(h,e),:] + bqk[(h,e)]
  mfma_gemm<true><<<dim3(mt,4,4), 256, 0, stream>>>(
      Ag, D, 0,  Gt16, D, D, 0,  qk16, H*D, 0, D,  C, D, bqk, nullptr, nullptr);

  seg_attn<<<(C + 7)/8, 256, 0, stream>>>(enc, rows, offsets, qk16, qb,
                                          Shat16, beta, C);

  // out[c,o] = Shat[c,:] @ Zt[o,:] + bo[o] + sum_h beta[c,h]*bvo[h,o]
  mfma_gemm<false><<<dim3(mt,4,1), 256, 0, stream>>>(
      Shat16, H*D, 0,  Zt16, H*D, 0, 0,  out, NOUT, 0, 0,  C, H*D, bo, beta, bvo);
}